// Round 3
// baseline (149.307 us; speedup 1.0000x reference)
//
#include <hip/hip_runtime.h>
#include <math.h>

#define TT 64

// wave-local LDS fence: waitcnt lgkmcnt(0) only; vmcnt untouched so global
// prefetch stays in flight. wave_barrier pins compiler ordering.
__device__ __forceinline__ void syncwave() {
    __builtin_amdgcn_wave_barrier();
    __builtin_amdgcn_s_waitcnt(0xC07F);   // vmcnt=63(no wait), expcnt=7, lgkmcnt=0
    __builtin_amdgcn_wave_barrier();
}

template<int OFF>
__device__ __forceinline__ float swz(float v) {
    return __int_as_float(__builtin_amdgcn_ds_swizzle(__float_as_int(v), OFF));
}
// BitMode offset = (xor<<10)|(or<<5)|and. Broadcast lane M within groups of 8
// (inside each 32-lane half): and=24, or=M -> OFF=(M<<5)|24. (verified R2)
#define BC8ALL(dst, src)                                            \
    dst[0] = swz<24>(src);  dst[1] = swz<56>(src);                  \
    dst[2] = swz<88>(src);  dst[3] = swz<120>(src);                 \
    dst[4] = swz<152>(src); dst[5] = swz<184>(src);                 \
    dst[6] = swz<216>(src); dst[7] = swz<248>(src);

// ---------------------------------------------------------------------------
// chains: block b = batch b; wave 0 = question chain, wave 1 = answer chain.
// Lane l = 8*j + i handles column j of U (32x8). Register state:
//   ub[m]  = Up[m][j]   (whole Up column, kept coherent across the 8-group)
//   uq[c]  = Uq[8c+i][j]
//   xr[c][m] = x[i][8c+m]  (row i of x)     -- depends only on i
//   xt[c][m] = x[m][8c+i]  (cols 8c+i of x) -- depends only on i
// Step (exact to O(X^3), verified R2):
//   s = x^T Up ; v = Uq + s ; t = x v ; Up' = Up - 2t ; Uq' = Uq + 2s - 2 x^T t
// Cross-lane: BC8(v) (24 swz) and BC8(t) (8 swz) -> 2 DS hops per step.
// x loaded directly from global in both layouts, prefetched one step ahead.
// Epilogue: wave 0 builds yb = cayley(bias) via exact 8x8 Gauss-Jordan in LDS
// (wave-synchronous) at kernel start, applies U <- yb U at the end.
// Distance: dist^2 = 16 - 2 ||U0^T U1||_F^2 (columns orthonormal).
// ---------------------------------------------------------------------------
__global__ __launch_bounds__(128, 1) void chains(
    const int* __restrict__ s1, const int* __restrict__ s2,
    const float* __restrict__ qemb, const float* __restrict__ aemb,
    const float* __restrict__ qtr, const float* __restrict__ qbias,
    const float* __restrict__ wf, const float* __restrict__ wb,
    float* __restrict__ out) {
    __shared__ float xb[192];
    __shared__ float Aug[8][16];
    __shared__ float Hm[192];
    __shared__ __align__(16) float ybs[1024];
    __shared__ __align__(16) float Ucm[2][8][32];   // [side][col][row]

    const int tid = threadIdx.x;
    const int s = tid >> 6;
    const int l = tid & 63;
    const int b = blockIdx.x;
    const int i = l & 7;
    const int j = l >> 3;

    // ---- wave 0: build yb (32x32) in LDS via exact Gauss-Jordan (wave-sync,
    // no __syncthreads; wave 1 races ahead into its chain).
    if (s == 0) {
        xb[l] = qbias[l]; xb[l + 64] = qbias[l + 64]; xb[l + 128] = qbias[l + 128];
        syncwave();
        const int gi = l >> 3, gj = l & 7;
        float a = (gi == gj) ? 1.0f : 0.0f;
        for (int k = 0; k < 24; ++k) a += xb[gi * 24 + k] * xb[gj * 24 + k];
        Aug[gi][gj] = a;
        Aug[gi][gj + 8] = (gi == gj) ? 1.0f : 0.0f;
        syncwave();
        for (int k = 0; k < 8; ++k) {
            const float piv = Aug[k][k];
            syncwave();
            if (gi == k) {
                const float ip = 1.0f / piv;
                Aug[k][gj] *= ip;
                Aug[k][gj + 8] *= ip;
            }
            syncwave();
            const float f = Aug[gi][k];
            syncwave();
            if (gi != k) {
                Aug[gi][gj]     -= f * Aug[k][gj];
                Aug[gi][gj + 8] -= f * Aug[k][gj + 8];
            }
            syncwave();
        }
        for (int idx = l; idx < 192; idx += 64) {
            const int r = idx / 24, c = idx % 24;
            float h = 0.0f;
            for (int m = 0; m < 8; ++m) h += Aug[r][8 + m] * xb[m * 24 + c];
            Hm[idx] = h;
        }
        syncwave();
        for (int idx = l; idx < 1024; idx += 64) {
            const int r = idx >> 5, c = idx & 31;
            float v;
            if (r < 8 && c < 8) {
                v = 2.0f * Aug[r][8 + c] - ((r == c) ? 1.0f : 0.0f);
            } else if (r < 8) {
                v = -2.0f * Hm[r * 24 + (c - 8)];
            } else if (c < 8) {
                v = 2.0f * Hm[c * 24 + (r - 8)];
            } else {
                float s2 = 0.0f;
                for (int m = 0; m < 8; ++m) s2 += xb[m * 24 + (r - 8)] * Hm[m * 24 + (c - 8)];
                v = ((r == c) ? 1.0f : 0.0f) - 2.0f * s2;
            }
            ybs[idx] = v;
        }
        syncwave();
    }

    const int* sent = s ? s2 : s1;
    const float* emb = s ? aemb : qemb;
    const int myid = sent[b * TT + l];

    // ---- transform coefficients in both layouts (q-side only; a-side = 1)
    float trr[3][8], trt[3][8];
    if (s == 0) {
        const float4* qr = (const float4*)(qtr + i * 24);
        #pragma unroll
        for (int u = 0; u < 6; ++u) {
            const float4 vv = qr[u];
            trr[u >> 1][(u & 1) * 4 + 0] = vv.x;
            trr[u >> 1][(u & 1) * 4 + 1] = vv.y;
            trr[u >> 1][(u & 1) * 4 + 2] = vv.z;
            trr[u >> 1][(u & 1) * 4 + 3] = vv.w;
        }
        #pragma unroll
        for (int c = 0; c < 3; ++c)
            #pragma unroll
            for (int m = 0; m < 8; ++m)
                trt[c][m] = qtr[m * 24 + 8 * c + i];
    } else {
        #pragma unroll
        for (int c = 0; c < 3; ++c)
            #pragma unroll
            for (int m = 0; m < 8; ++m) { trr[c][m] = 1.0f; trt[c][m] = 1.0f; }
    }

    // ---- state
    float ub[8];
    #pragma unroll
    for (int m = 0; m < 8; ++m) ub[m] = (m == j) ? 1.0f : 0.0f;
    float uq0 = 0.0f, uq1 = 0.0f, uq2 = 0.0f;

    float xr[3][8], xt[3][8];
    {   // preload token TT-1 in both layouts
        const int id = __shfl(myid, TT - 1);
        const float* base = emb + (size_t)id * 192;
        const float4* br = (const float4*)(base + i * 24);
        #pragma unroll
        for (int u = 0; u < 6; ++u) {
            const float4 vv = br[u];
            const int c = u >> 1, m0 = (u & 1) * 4;
            xr[c][m0 + 0] = vv.x * trr[c][m0 + 0];
            xr[c][m0 + 1] = vv.y * trr[c][m0 + 1];
            xr[c][m0 + 2] = vv.z * trr[c][m0 + 2];
            xr[c][m0 + 3] = vv.w * trr[c][m0 + 3];
        }
        const float* bc = base + i;
        #pragma unroll
        for (int c = 0; c < 3; ++c)
            #pragma unroll
            for (int m = 0; m < 8; ++m)
                xt[c][m] = bc[m * 24 + 8 * c] * trt[c][m];
    }

    for (int t = TT - 1; t >= 0; --t) {
        // ---- prefetch next token (both layouts) -- independent global loads,
        // consumed only at the bottom of this iteration.
        float4 nr[6];
        float nt[3][8];
        if (t > 0) {
            const int id2 = __shfl(myid, t - 1);
            const float* base2 = emb + (size_t)id2 * 192;
            const float4* br2 = (const float4*)(base2 + i * 24);
            #pragma unroll
            for (int u = 0; u < 6; ++u) nr[u] = br2[u];
            const float* bc2 = base2 + i;
            #pragma unroll
            for (int c = 0; c < 3; ++c)
                #pragma unroll
                for (int m = 0; m < 8; ++m)
                    nt[c][m] = bc2[m * 24 + 8 * c];
        }

        // ---- s = x^T Up (local), v = Uq + s
        float sc[3];
        #pragma unroll
        for (int c = 0; c < 3; ++c) {
            float a0 = fmaf(xt[c][1], ub[1], xt[c][0] * ub[0]);
            float a1 = fmaf(xt[c][3], ub[3], xt[c][2] * ub[2]);
            float a2 = fmaf(xt[c][5], ub[5], xt[c][4] * ub[4]);
            float a3 = fmaf(xt[c][7], ub[7], xt[c][6] * ub[6]);
            sc[c] = (a0 + a1) + (a2 + a3);
        }
        const float v0 = uq0 + sc[0], v1 = uq1 + sc[1], v2 = uq2 + sc[2];

        // ---- hop 1: broadcast v (full 24-vector per lane)
        float vb0[8], vb1[8], vb2[8];
        BC8ALL(vb0, v0);
        BC8ALL(vb1, v1);
        BC8ALL(vb2, v2);

        // ---- t_i = <row i of x, v>  (local)
        float p0, p1, p2;
        {
            float a0 = fmaf(xr[0][1], vb0[1], xr[0][0] * vb0[0]);
            float a1 = fmaf(xr[0][3], vb0[3], xr[0][2] * vb0[2]);
            float a2 = fmaf(xr[0][5], vb0[5], xr[0][4] * vb0[4]);
            float a3 = fmaf(xr[0][7], vb0[7], xr[0][6] * vb0[6]);
            p0 = (a0 + a1) + (a2 + a3);
        }
        {
            float a0 = fmaf(xr[1][1], vb1[1], xr[1][0] * vb1[0]);
            float a1 = fmaf(xr[1][3], vb1[3], xr[1][2] * vb1[2]);
            float a2 = fmaf(xr[1][5], vb1[5], xr[1][4] * vb1[4]);
            float a3 = fmaf(xr[1][7], vb1[7], xr[1][6] * vb1[6]);
            p1 = (a0 + a1) + (a2 + a3);
        }
        {
            float a0 = fmaf(xr[2][1], vb2[1], xr[2][0] * vb2[0]);
            float a1 = fmaf(xr[2][3], vb2[3], xr[2][2] * vb2[2]);
            float a2 = fmaf(xr[2][5], vb2[5], xr[2][4] * vb2[4]);
            float a3 = fmaf(xr[2][7], vb2[7], xr[2][6] * vb2[6]);
            p2 = (a0 + a1) + (a2 + a3);
        }
        const float ti = (p0 + p1) + p2;

        // ---- hop 2: broadcast t
        float tb[8];
        BC8ALL(tb, ti);

        // ---- Up' = Up - 2t  (whole column, registers)
        #pragma unroll
        for (int m = 0; m < 8; ++m) ub[m] = fmaf(-2.0f, tb[m], ub[m]);

        // ---- Uq' = Uq + 2s - 2 x^T t  (local)
        {
            float a0 = fmaf(xt[0][1], tb[1], xt[0][0] * tb[0]);
            float a1 = fmaf(xt[0][3], tb[3], xt[0][2] * tb[2]);
            float a2 = fmaf(xt[0][5], tb[5], xt[0][4] * tb[4]);
            float a3 = fmaf(xt[0][7], tb[7], xt[0][6] * tb[6]);
            uq0 += 2.0f * (sc[0] - ((a0 + a1) + (a2 + a3)));
        }
        {
            float a0 = fmaf(xt[1][1], tb[1], xt[1][0] * tb[0]);
            float a1 = fmaf(xt[1][3], tb[3], xt[1][2] * tb[2]);
            float a2 = fmaf(xt[1][5], tb[5], xt[1][4] * tb[4]);
            float a3 = fmaf(xt[1][7], tb[7], xt[1][6] * tb[6]);
            uq1 += 2.0f * (sc[1] - ((a0 + a1) + (a2 + a3)));
        }
        {
            float a0 = fmaf(xt[2][1], tb[1], xt[2][0] * tb[0]);
            float a1 = fmaf(xt[2][3], tb[3], xt[2][2] * tb[2]);
            float a2 = fmaf(xt[2][5], tb[5], xt[2][4] * tb[4]);
            float a3 = fmaf(xt[2][7], tb[7], xt[2][6] * tb[6]);
            uq2 += 2.0f * (sc[2] - ((a0 + a1) + (a2 + a3)));
        }

        // ---- commit prefetch (apply transform coefficients)
        if (t > 0) {
            #pragma unroll
            for (int u = 0; u < 6; ++u) {
                const int c = u >> 1, m0 = (u & 1) * 4;
                xr[c][m0 + 0] = nr[u].x * trr[c][m0 + 0];
                xr[c][m0 + 1] = nr[u].y * trr[c][m0 + 1];
                xr[c][m0 + 2] = nr[u].z * trr[c][m0 + 2];
                xr[c][m0 + 3] = nr[u].w * trr[c][m0 + 3];
            }
            #pragma unroll
            for (int c = 0; c < 3; ++c)
                #pragma unroll
                for (int m = 0; m < 8; ++m)
                    xt[c][m] = nt[c][m] * trt[c][m];
        }
    }

    // ---- q-side: U <- yb U  (yb in LDS, Uq broadcast within group)
    if (s == 0) {
        float uqb0[8], uqb1[8], uqb2[8];
        BC8ALL(uqb0, uq0);
        BC8ALL(uqb1, uq1);
        BC8ALL(uqb2, uq2);
        float nu[4];
        #pragma unroll
        for (int c4 = 0; c4 < 4; ++c4) {
            const int r = i + 8 * c4;
            const float* yr = &ybs[r * 32];
            float acc = 0.0f;
            #pragma unroll
            for (int m = 0; m < 8; ++m) acc = fmaf(yr[m],      ub[m],   acc);
            #pragma unroll
            for (int m = 0; m < 8; ++m) acc = fmaf(yr[8 + m],  uqb0[m], acc);
            #pragma unroll
            for (int m = 0; m < 8; ++m) acc = fmaf(yr[16 + m], uqb1[m], acc);
            #pragma unroll
            for (int m = 0; m < 8; ++m) acc = fmaf(yr[24 + m], uqb2[m], acc);
            nu[c4] = acc;
        }
        Ucm[0][j][i]      = nu[0];
        Ucm[0][j][8 + i]  = nu[1];
        Ucm[0][j][16 + i] = nu[2];
        Ucm[0][j][24 + i] = nu[3];
    } else {
        if (i == 0) {
            #pragma unroll
            for (int m = 0; m < 8; ++m) Ucm[1][j][m] = ub[m];
        }
        Ucm[1][j][8 + i]  = uq0;
        Ucm[1][j][16 + i] = uq1;
        Ucm[1][j][24 + i] = uq2;
    }
    __syncthreads();

    // ---- join: dist^2 = 16 - 2 ||U0^T U1||_F^2
    if (s == 0) {
        const int a = l >> 3, bb = l & 7;
        const float4* ca = (const float4*)&Ucm[0][a][0];
        const float4* cb = (const float4*)&Ucm[1][bb][0];
        float acc = 0.0f;
        #pragma unroll
        for (int u = 0; u < 8; ++u) {
            const float4 A = ca[u], B = cb[u];
            acc += A.x * B.x + A.y * B.y + A.z * B.z + A.w * B.w;
        }
        float val = acc * acc;
        #pragma unroll
        for (int d = 1; d < 64; d <<= 1) val += __shfl_xor(val, d);
        if (l == 0) {
            const float d2 = 16.0f - 2.0f * val;
            out[b] = -wf[0] * sqrtf(fmaxf(d2, 0.0f)) + wb[0];
        }
    }
}

extern "C" void kernel_launch(void* const* d_in, const int* in_sizes, int n_in,
                              void* d_out, int out_size, void* d_ws, size_t ws_size,
                              hipStream_t stream) {
    const int* s1 = (const int*)d_in[0];
    const int* s2 = (const int*)d_in[1];
    const float* qemb  = (const float*)d_in[2];
    const float* aemb  = (const float*)d_in[3];
    const float* qtr   = (const float*)d_in[4];
    const float* qbias = (const float*)d_in[5];
    const float* wf    = (const float*)d_in[6];
    const float* wb    = (const float*)d_in[7];
    float* out = (float*)d_out;
    (void)d_ws; (void)ws_size; (void)in_sizes; (void)n_in; (void)out_size;

    chains<<<512, 128, 0, stream>>>(s1, s2, qemb, aemb, qtr, qbias, wf, wb, out);
}